// Round 4
// baseline (898.740 us; speedup 1.0000x reference)
//
#include <hip/hip_runtime.h>
#include <hip/hip_bf16.h>
#include <cstdint>
#include <math.h>

#define EMBED 1024
#define HEADS 16
#define HDIM 64
#define SEQ 2048
#define TOKENS 8192   // 4*2048

typedef __attribute__((ext_vector_type(8))) short short8;
typedef __attribute__((ext_vector_type(4))) float f32x4;
typedef unsigned short ushort_t;

__device__ __forceinline__ float bf2f(ushort_t u) {
  union { unsigned int i; float f; } c; c.i = ((unsigned int)u) << 16; return c.f;
}
__device__ __forceinline__ ushort_t f2bf(float f) {
  union { float f; unsigned int i; } c; c.f = f;
  unsigned int x = c.i;
  unsigned int r = x + 0x7fffu + ((x >> 16) & 1u);  // RNE
  return (ushort_t)(r >> 16);
}
__device__ __forceinline__ bool in_is_f32(const void* flagsrc) {
  // ln1_g is all-ones: f32 -> 0x3F800000 ; bf16 pair -> 0x3F803F80
  return *(const unsigned int*)flagsrc == 0x3F800000u;
}
__device__ __forceinline__ float load_in(const void* p, long i, bool f32) {
  return f32 ? ((const float*)p)[i] : bf2f(((const ushort_t*)p)[i]);
}
__device__ __forceinline__ void g2lds16(const void* g, void* l) {
  __builtin_amdgcn_global_load_lds(
      (const __attribute__((address_space(1))) unsigned int*)g,
      (__attribute__((address_space(3))) unsigned int*)l, 16, 0, 0);
}

// ---------- prep: convert any-dtype input to f32 (grid-stride) ----------
__global__ __launch_bounds__(256) void cvt_f32_k(const void* __restrict__ in,
                                                 const void* __restrict__ flagsrc,
                                                 float* __restrict__ out, long n) {
  bool f32 = in_is_f32(flagsrc);
  long i = (long)blockIdx.x * blockDim.x + threadIdx.x;
  long stride = (long)gridDim.x * blockDim.x;
  for (; i < n; i += stride) out[i] = load_in(in, i, f32);
}

// ---------- prep: transpose + cast to bf16: out[c][r] = bf16(in[r][c]) ------
__global__ __launch_bounds__(256) void transpose_dual_k(const void* __restrict__ in,
                                                        const void* __restrict__ flagsrc,
                                                        ushort_t* __restrict__ out,
                                                        int R, int C) {
  bool f32 = in_is_f32(flagsrc);
  __shared__ ushort_t tile[32][33];
  int tx = threadIdx.x & 31, ty = threadIdx.x >> 5;
  int c0 = blockIdx.x * 32, r0 = blockIdx.y * 32;
#pragma unroll
  for (int i = ty; i < 32; i += 8)
    tile[i][tx] = f2bf(load_in(in, (long)(r0 + i) * C + (c0 + tx), f32));
  __syncthreads();
#pragma unroll
  for (int i = ty; i < 32; i += 8) out[(long)(c0 + i) * R + (r0 + tx)] = tile[tx][i];
}

// ---------- layernorm rows of 1024, f32 in -> bf16 out ----------
__global__ __launch_bounds__(256) void ln_k(const float* __restrict__ xin,
                                            const float* __restrict__ g,
                                            const float* __restrict__ b,
                                            ushort_t* __restrict__ out) {
  int row = blockIdx.x, t = threadIdx.x;
  long base = (long)row * EMBED + t * 4;
  f32x4 xv = *(const f32x4*)(xin + base);
  float v[4] = {xv[0], xv[1], xv[2], xv[3]};
  float s1 = v[0] + v[1] + v[2] + v[3];
  float s2 = v[0]*v[0] + v[1]*v[1] + v[2]*v[2] + v[3]*v[3];
#pragma unroll
  for (int m = 1; m < 64; m <<= 1) { s1 += __shfl_xor(s1, m, 64); s2 += __shfl_xor(s2, m, 64); }
  __shared__ float ws1[4], ws2[4];
  int w = t >> 6, lane = t & 63;
  if (lane == 0) { ws1[w] = s1; ws2[w] = s2; }
  __syncthreads();
  float S1 = ws1[0] + ws1[1] + ws1[2] + ws1[3];
  float S2 = ws2[0] + ws2[1] + ws2[2] + ws2[3];
  float mean = S1 * (1.0f / EMBED);
  float var = S2 * (1.0f / EMBED) - mean * mean;
  float rstd = rsqrtf(var + 1e-5f);
#pragma unroll
  for (int j = 0; j < 4; ++j) {
    int c = t * 4 + j;
    out[(long)row * EMBED + c] = f2bf((v[j] - mean) * rstd * g[c] + b[c]);
  }
}

// ---------------- fused QKV: [131072,64] x (64x64)^T x3 ----------------
__global__ __launch_bounds__(256) void qkv_k(const ushort_t* __restrict__ xn,
                                             const ushort_t* __restrict__ WqT,
                                             const ushort_t* __restrict__ WkT,
                                             const ushort_t* __restrict__ WvT,
                                             ushort_t* __restrict__ q, ushort_t* __restrict__ k,
                                             ushort_t* __restrict__ v) {
  __shared__ __align__(16) ushort_t As[128 * 64];  // 16KB
  int t = threadIdx.x;
  long rowbase = (long)blockIdx.x * 128;
#pragma unroll
  for (int p = 0; p < 4; ++p) {
    int idx = p * 256 + t;             // 1024 chunks of 16B
    int row = idx >> 3, chunk = idx & 7;
    g2lds16(xn + (rowbase + row) * 64 + chunk * 8, As + idx * 8);
  }
  __syncthreads();
  int w = t >> 6, lane = t & 63, l15 = lane & 15, quad = lane >> 4;
  short8 af[2][2];
#pragma unroll
  for (int mi = 0; mi < 2; ++mi)
#pragma unroll
    for (int ks = 0; ks < 2; ++ks)
      af[mi][ks] = *(const short8*)(As + (w * 32 + mi * 16 + l15) * 64 + ks * 32 + quad * 8);
  const ushort_t* Ws[3] = {WqT, WkT, WvT};
  ushort_t* Os[3] = {q, k, v};
#pragma unroll
  for (int wsel = 0; wsel < 3; ++wsel) {
    const ushort_t* W = Ws[wsel];
    short8 bfr[4][2];
#pragma unroll
    for (int ni = 0; ni < 4; ++ni)
#pragma unroll
      for (int ks = 0; ks < 2; ++ks)
        bfr[ni][ks] = *(const short8*)(W + (ni * 16 + l15) * 64 + ks * 32 + quad * 8);
    f32x4 acc[2][4] = {};
#pragma unroll
    for (int mi = 0; mi < 2; ++mi)
#pragma unroll
      for (int ni = 0; ni < 4; ++ni)
#pragma unroll
        for (int ks = 0; ks < 2; ++ks)
          acc[mi][ni] = __builtin_amdgcn_mfma_f32_16x16x32_bf16(af[mi][ks], bfr[ni][ks],
                                                                acc[mi][ni], 0, 0, 0);
    ushort_t* O = Os[wsel];
#pragma unroll
    for (int mi = 0; mi < 2; ++mi)
#pragma unroll
      for (int ni = 0; ni < 4; ++ni)
#pragma unroll
        for (int r = 0; r < 4; ++r) {
          long rg = rowbase + w * 32 + mi * 16 + quad * 4 + r;
          O[rg * 64 + ni * 16 + l15] = f2bf(acc[mi][ni][r]);
        }
  }
}

// ---------------- flash attention: grid (32 qtiles, 64 batch-heads) ---------
__global__ __launch_bounds__(256) void attn_k(const ushort_t* __restrict__ q,
                                              const ushort_t* __restrict__ kk,
                                              const ushort_t* __restrict__ vv,
                                              ushort_t* __restrict__ ctx) {
  __shared__ __align__(16) ushort_t sm[16384];  // Qs|Ks|Vt|Ps, 8KB each
  ushort_t* Qs = sm;
  ushort_t* Ks = sm + 4096;
  ushort_t* Vt = sm + 8192;
  ushort_t* Ps = sm + 12288;
  int t = threadIdx.x;
  int qt = blockIdx.x, bh = blockIdx.y;
  int n = bh >> 4, h = bh & 15;
  long qtok0 = (long)n * SEQ + qt * 64;
#pragma unroll
  for (int p = 0; p < 2; ++p) {
    int idx = p * 256 + t;
    int row = idx >> 3, chunk = idx & 7;
    g2lds16(q + (qtok0 + row) * EMBED + h * HDIM + chunk * 8, Qs + idx * 8);
  }
  int w = t >> 6, lane = t & 63, l15 = lane & 15, quad = lane >> 4;
  float m_run[4] = {-1e30f, -1e30f, -1e30f, -1e30f};
  float l_run[4] = {0.f, 0.f, 0.f, 0.f};
  f32x4 acc_o[4] = {};
  const float sc = 1.0f / 32.0f;  // 1/sqrt(EMBED)
  for (int kt = 0; kt < SEQ / 64; ++kt) {
    long ktok0 = (long)n * SEQ + kt * 64;
    __syncthreads();  // previous tile's readers done (also drains Qs loads at kt=0)
#pragma unroll
    for (int p = 0; p < 2; ++p) {
      int idx = p * 256 + t;
      int row = idx >> 3, chunk = idx & 7;
      g2lds16(kk + (ktok0 + row) * EMBED + h * HDIM + chunk * 8, Ks + idx * 8);
    }
#pragma unroll
    for (int p = 0; p < 2; ++p) {
      int idx = p * 256 + t;
      int key = idx >> 3, chunk = idx & 7;
      short8 val = *(const short8*)(vv + (ktok0 + key) * EMBED + h * HDIM + chunk * 8);
#pragma unroll
      for (int j = 0; j < 8; ++j) Vt[(chunk * 8 + j) * 64 + key] = (ushort_t)val[j];
    }
    __syncthreads();
    // S = Q K^T  (16 q-rows per wave x 64 keys)
    f32x4 s[4] = {};
#pragma unroll
    for (int ks = 0; ks < 2; ++ks) {
      short8 a = *(const short8*)(Qs + (w * 16 + l15) * 64 + ks * 32 + quad * 8);
#pragma unroll
      for (int nf = 0; nf < 4; ++nf) {
        short8 bb = *(const short8*)(Ks + (nf * 16 + l15) * 64 + ks * 32 + quad * 8);
        s[nf] = __builtin_amdgcn_mfma_f32_16x16x32_bf16(a, bb, s[nf], 0, 0, 0);
      }
    }
#pragma unroll
    for (int nf = 0; nf < 4; ++nf)
#pragma unroll
      for (int j = 0; j < 4; ++j) s[nf][j] *= sc;
    // online softmax; lane holds rows quad*4+j, cols nf*16+l15
    float mnew[4], alpha[4];
#pragma unroll
    for (int j = 0; j < 4; ++j) {
      float m = fmaxf(fmaxf(s[0][j], s[1][j]), fmaxf(s[2][j], s[3][j]));
#pragma unroll
      for (int d = 1; d < 16; d <<= 1) m = fmaxf(m, __shfl_xor(m, d, 64));
      mnew[j] = fmaxf(m_run[j], m);
      alpha[j] = __expf(m_run[j] - mnew[j]);
      m_run[j] = mnew[j];
    }
    float rsum[4] = {0.f, 0.f, 0.f, 0.f};
#pragma unroll
    for (int nf = 0; nf < 4; ++nf)
#pragma unroll
      for (int j = 0; j < 4; ++j) {
        float p = __expf(s[nf][j] - mnew[j]);
        s[nf][j] = p;
        rsum[j] += p;
      }
#pragma unroll
    for (int j = 0; j < 4; ++j) {
      float r = rsum[j];
#pragma unroll
      for (int d = 1; d < 16; d <<= 1) r += __shfl_xor(r, d, 64);
      l_run[j] = l_run[j] * alpha[j] + r;
    }
#pragma unroll
    for (int nf = 0; nf < 4; ++nf)
#pragma unroll
      for (int j = 0; j < 4; ++j) acc_o[nf][j] *= alpha[j];
    // P -> LDS (bf16, A-operand layout round-trip); wave-private region
    ushort_t* Pw = Ps + w * 1024;
#pragma unroll
    for (int nf = 0; nf < 4; ++nf)
#pragma unroll
      for (int j = 0; j < 4; ++j)
        Pw[(quad * 4 + j) * 64 + nf * 16 + l15] = f2bf(s[nf][j]);
    // O += P V
#pragma unroll
    for (int ks = 0; ks < 2; ++ks) {
      short8 a = *(const short8*)(Pw + l15 * 64 + ks * 32 + quad * 8);
#pragma unroll
      for (int nf = 0; nf < 4; ++nf) {
        short8 bb = *(const short8*)(Vt + (nf * 16 + l15) * 64 + ks * 32 + quad * 8);
        acc_o[nf] = __builtin_amdgcn_mfma_f32_16x16x32_bf16(a, bb, acc_o[nf], 0, 0, 0);
      }
    }
  }
#pragma unroll
  for (int nf = 0; nf < 4; ++nf)
#pragma unroll
    for (int j = 0; j < 4; ++j) {
      long tok = qtok0 + w * 16 + quad * 4 + j;
      float inv_l = 1.0f / fmaxf(l_run[j], 1e-30f);
      ctx[(tok * HEADS + h) * HDIM + nf * 16 + l15] = f2bf(acc_o[nf][j] * inv_l);
    }
}

// ---------------- gemm_bt 128x128, BK=32, fused epilogues -------------------
// mode 0: out_f  = acc + bias + res        (f32 out; res = x, f32)
// mode 1: out_bf = gelu_exact(acc + bias)
// mode 2: out_f  = acc + bias + res        (f32 OUT -> d_out; res = attn_out, f32)
__global__ __launch_bounds__(256) void gemm_bt(const ushort_t* __restrict__ A,
                                               const ushort_t* __restrict__ BT,
                                               const float* __restrict__ bias,
                                               const float* __restrict__ res,
                                               ushort_t* __restrict__ out_bf,
                                               float* __restrict__ out_f,
                                               int M, int N, int K, int mode) {
  __shared__ __align__(16) ushort_t As[128 * 32];
  __shared__ __align__(16) ushort_t Bs[128 * 32];
  int t = threadIdx.x;
  long m0 = (long)blockIdx.y * 128;
  long n0 = (long)blockIdx.x * 128;
  int w = t >> 6, lane = t & 63, l15 = lane & 15, quad = lane >> 4;
  int wm = w >> 1, wn = w & 1;
  f32x4 acc[4][4] = {};
  for (int kt = 0; kt < K; kt += 32) {
    __syncthreads();
#pragma unroll
    for (int p = 0; p < 2; ++p) {
      int idx = p * 256 + t;         // 512 chunks of 16B per tile
      int row = idx >> 2, chunk = idx & 3;
      g2lds16(A + (m0 + row) * K + kt + chunk * 8, As + idx * 8);
      g2lds16(BT + (n0 + row) * K + kt + chunk * 8, Bs + idx * 8);
    }
    __syncthreads();
    short8 af[4], bfr[4];
#pragma unroll
    for (int mi = 0; mi < 4; ++mi)
      af[mi] = *(const short8*)(As + (wm * 64 + mi * 16 + l15) * 32 + quad * 8);
#pragma unroll
    for (int ni = 0; ni < 4; ++ni)
      bfr[ni] = *(const short8*)(Bs + (wn * 64 + ni * 16 + l15) * 32 + quad * 8);
#pragma unroll
    for (int mi = 0; mi < 4; ++mi)
#pragma unroll
      for (int ni = 0; ni < 4; ++ni)
        acc[mi][ni] = __builtin_amdgcn_mfma_f32_16x16x32_bf16(af[mi], bfr[ni], acc[mi][ni], 0, 0, 0);
  }
#pragma unroll
  for (int mi = 0; mi < 4; ++mi)
#pragma unroll
    for (int ni = 0; ni < 4; ++ni) {
      long col = n0 + wn * 64 + ni * 16 + l15;
      float bv = bias[col];
#pragma unroll
      for (int r = 0; r < 4; ++r) {
        long row = m0 + wm * 64 + mi * 16 + quad * 4 + r;
        long off = row * N + col;
        float val = acc[mi][ni][r] + bv;
        if (mode == 0) {
          out_f[off] = val + res[off];
        } else if (mode == 1) {
          val = 0.5f * val * (1.0f + erff(val * 0.70710678118654752f));
          out_bf[off] = f2bf(val);
        } else {
          out_f[off] = val + res[off];   // f32 final output
        }
      }
    }
}

extern "C" void kernel_launch(void* const* d_in, const int* in_sizes, int n_in,
                              void* d_out, int out_size, void* d_ws, size_t ws_size,
                              hipStream_t stream) {
  (void)in_sizes; (void)n_in; (void)out_size; (void)ws_size;
  const void* x   = d_in[0];
  const void* Wq  = d_in[1];
  const void* Wk  = d_in[2];
  const void* Wv  = d_in[3];
  const void* Wo  = d_in[4];
  const void* bo  = d_in[5];
  const void* l1g = d_in[6];   // all-ones: dtype flag source
  const void* l1b = d_in[7];
  const void* l2g = d_in[8];
  const void* l2b = d_in[9];
  const void* W1  = d_in[10];
  const void* b1  = d_in[11];
  const void* W2  = d_in[12];
  const void* b2  = d_in[13];
  const void* FLAG = l1g;
  float* out = (float*)d_out;

  char* ws = (char*)d_ws;
  const size_t MB = 1ull << 20;
  float*    XF  = (float*)(ws);               // 32MB  [0,32)
  ushort_t* XN  = (ushort_t*)(ws + 32 * MB);  // 16MB  [32,48) ; reused as CTX
  ushort_t* Q   = (ushort_t*)(ws + 48 * MB);  // 16MB  [48,64)
  ushort_t* Kb  = (ushort_t*)(ws + 64 * MB);  // 16MB  [64,80)
  ushort_t* Vb  = (ushort_t*)(ws + 80 * MB);  // 16MB  [80,96)
  float*    AO  = (float*)(ws + 64 * MB);     // 32MB  [64,96) over Kb/Vb (dead by then)
  ushort_t* CTX = XN;
  ushort_t* AN  = (ushort_t*)(ws + 96 * MB);  // 16MB  [96,112)
  ushort_t* FF1 = (ushort_t*)(ws);            // 64MB  [0,64) over XF/XN/Q (dead by mode-1)
  ushort_t* WoT = (ushort_t*)(ws + 112 * MB); // 2MB
  ushort_t* W1T = (ushort_t*)(ws + 114 * MB); // 8MB
  ushort_t* W2T = (ushort_t*)(ws + 122 * MB); // 8MB
  ushort_t* WqT = (ushort_t*)(ws + 130 * MB);
  ushort_t* WkT = WqT + 4096;
  ushort_t* WvT = WkT + 4096;
  float* BOf = (float*)(ws + 131 * MB);       // 1024
  float* B1f = BOf + 1024;                    // 4096
  float* B2f = B1f + 4096;                    // 1024
  float* G1f = B2f + 1024;
  float* Bt1f = G1f + 1024;
  float* G2f = Bt1f + 1024;
  float* Bt2f = G2f + 1024;                   // ends < 132MB

  dim3 b256(256);
  // --- prep: normalize dtypes (flag-driven) ---
  cvt_f32_k<<<dim3(2048), b256, 0, stream>>>(x, FLAG, XF, (long)TOKENS * EMBED);
  cvt_f32_k<<<dim3(4), b256, 0, stream>>>(bo, FLAG, BOf, 1024);
  cvt_f32_k<<<dim3(16), b256, 0, stream>>>(b1, FLAG, B1f, 4096);
  cvt_f32_k<<<dim3(4), b256, 0, stream>>>(b2, FLAG, B2f, 1024);
  cvt_f32_k<<<dim3(4), b256, 0, stream>>>(l1g, FLAG, G1f, 1024);
  cvt_f32_k<<<dim3(4), b256, 0, stream>>>(l1b, FLAG, Bt1f, 1024);
  cvt_f32_k<<<dim3(4), b256, 0, stream>>>(l2g, FLAG, G2f, 1024);
  cvt_f32_k<<<dim3(4), b256, 0, stream>>>(l2b, FLAG, Bt2f, 1024);
  transpose_dual_k<<<dim3(2, 2), b256, 0, stream>>>(Wq, FLAG, WqT, 64, 64);
  transpose_dual_k<<<dim3(2, 2), b256, 0, stream>>>(Wk, FLAG, WkT, 64, 64);
  transpose_dual_k<<<dim3(2, 2), b256, 0, stream>>>(Wv, FLAG, WvT, 64, 64);
  transpose_dual_k<<<dim3(32, 32), b256, 0, stream>>>(Wo, FLAG, WoT, 1024, 1024);
  transpose_dual_k<<<dim3(128, 32), b256, 0, stream>>>(W1, FLAG, W1T, 1024, 4096);
  transpose_dual_k<<<dim3(32, 128), b256, 0, stream>>>(W2, FLAG, W2T, 4096, 1024);

  // --- compute (fixed dtypes) ---
  ln_k<<<dim3(TOKENS), b256, 0, stream>>>(XF, G1f, Bt1f, XN);
  qkv_k<<<dim3(1024), b256, 0, stream>>>(XN, WqT, WkT, WvT, Q, Kb, Vb);
  attn_k<<<dim3(32, 64), b256, 0, stream>>>(Q, Kb, Vb, CTX);
  gemm_bt<<<dim3(8, 64), b256, 0, stream>>>(CTX, WoT, BOf, XF, nullptr, AO,
                                            TOKENS, EMBED, EMBED, 0);
  ln_k<<<dim3(TOKENS), b256, 0, stream>>>(AO, G2f, Bt2f, AN);
  gemm_bt<<<dim3(32, 64), b256, 0, stream>>>(AN, W1T, B1f, nullptr, FF1, nullptr,
                                             TOKENS, 4096, EMBED, 1);
  gemm_bt<<<dim3(8, 64), b256, 0, stream>>>(FF1, W2T, B2f, AO, nullptr, out,
                                            TOKENS, EMBED, 4096, 2);
}

// Round 5
// 724.113 us; speedup vs baseline: 1.2412x; 1.2412x over previous
//
#include <hip/hip_runtime.h>
#include <hip/hip_bf16.h>
#include <cstdint>
#include <math.h>

#define EMBED 1024
#define HEADS 16
#define HDIM 64
#define SEQ 2048
#define TOKENS 8192   // 4*2048

typedef __attribute__((ext_vector_type(8))) short short8;
typedef __attribute__((ext_vector_type(4))) float f32x4;
typedef unsigned short ushort_t;

__device__ __forceinline__ float bf2f(ushort_t u) {
  union { unsigned int i; float f; } c; c.i = ((unsigned int)u) << 16; return c.f;
}
__device__ __forceinline__ ushort_t f2bf(float f) {
  union { float f; unsigned int i; } c; c.f = f;
  unsigned int x = c.i;
  unsigned int r = x + 0x7fffu + ((x >> 16) & 1u);  // RNE
  return (ushort_t)(r >> 16);
}
__device__ __forceinline__ void g2lds16(const void* g, void* l) {
  __builtin_amdgcn_global_load_lds(
      (const __attribute__((address_space(1))) unsigned int*)g,
      (__attribute__((address_space(3))) unsigned int*)l, 16, 0, 0);
}

// ---------- prep: transpose + cast f32 -> bf16: out[c][r] = bf16(in[r][c]) --
__global__ __launch_bounds__(256) void transpose_cast_k(const float* __restrict__ in,
                                                        ushort_t* __restrict__ out,
                                                        int R, int C) {
  __shared__ ushort_t tile[32][33];
  int tx = threadIdx.x & 31, ty = threadIdx.x >> 5;
  int c0 = blockIdx.x * 32, r0 = blockIdx.y * 32;
#pragma unroll
  for (int i = ty; i < 32; i += 8)
    tile[i][tx] = f2bf(in[(long)(r0 + i) * C + (c0 + tx)]);
  __syncthreads();
#pragma unroll
  for (int i = ty; i < 32; i += 8) out[(long)(c0 + i) * R + (r0 + tx)] = tile[tx][i];
}

// ---------- layernorm rows of 1024, f32 in -> bf16 out ----------
__global__ __launch_bounds__(256) void ln_k(const float* __restrict__ xin,
                                            const float* __restrict__ g,
                                            const float* __restrict__ b,
                                            ushort_t* __restrict__ out) {
  int row = blockIdx.x, t = threadIdx.x;
  long base = (long)row * EMBED + t * 4;
  f32x4 xv = *(const f32x4*)(xin + base);
  float v[4] = {xv[0], xv[1], xv[2], xv[3]};
  float s1 = v[0] + v[1] + v[2] + v[3];
  float s2 = v[0]*v[0] + v[1]*v[1] + v[2]*v[2] + v[3]*v[3];
#pragma unroll
  for (int m = 1; m < 64; m <<= 1) { s1 += __shfl_xor(s1, m, 64); s2 += __shfl_xor(s2, m, 64); }
  __shared__ float ws1[4], ws2[4];
  int w = t >> 6, lane = t & 63;
  if (lane == 0) { ws1[w] = s1; ws2[w] = s2; }
  __syncthreads();
  float S1 = ws1[0] + ws1[1] + ws1[2] + ws1[3];
  float S2 = ws2[0] + ws2[1] + ws2[2] + ws2[3];
  float mean = S1 * (1.0f / EMBED);
  float var = S2 * (1.0f / EMBED) - mean * mean;
  float rstd = rsqrtf(var + 1e-5f);
#pragma unroll
  for (int j = 0; j < 4; ++j) {
    int c = t * 4 + j;
    out[(long)row * EMBED + c] = f2bf((v[j] - mean) * rstd * g[c] + b[c]);
  }
}

// ---------------- fused QKV: [131072,64] x (64x64)^T x3 ----------------
__global__ __launch_bounds__(256) void qkv_k(const ushort_t* __restrict__ xn,
                                             const ushort_t* __restrict__ WqT,
                                             const ushort_t* __restrict__ WkT,
                                             const ushort_t* __restrict__ WvT,
                                             ushort_t* __restrict__ q, ushort_t* __restrict__ k,
                                             ushort_t* __restrict__ v) {
  __shared__ __align__(16) ushort_t As[128 * 64];  // 16KB
  int t = threadIdx.x;
  long rowbase = (long)blockIdx.x * 128;
#pragma unroll
  for (int p = 0; p < 4; ++p) {
    int idx = p * 256 + t;             // 1024 chunks of 16B
    int row = idx >> 3, chunk = idx & 7;
    g2lds16(xn + (rowbase + row) * 64 + chunk * 8, As + idx * 8);
  }
  __syncthreads();
  int w = t >> 6, lane = t & 63, l15 = lane & 15, quad = lane >> 4;
  short8 af[2][2];
#pragma unroll
  for (int mi = 0; mi < 2; ++mi)
#pragma unroll
    for (int ks = 0; ks < 2; ++ks)
      af[mi][ks] = *(const short8*)(As + (w * 32 + mi * 16 + l15) * 64 + ks * 32 + quad * 8);
  const ushort_t* Ws[3] = {WqT, WkT, WvT};
  ushort_t* Os[3] = {q, k, v};
#pragma unroll
  for (int wsel = 0; wsel < 3; ++wsel) {
    const ushort_t* W = Ws[wsel];
    short8 bfr[4][2];
#pragma unroll
    for (int ni = 0; ni < 4; ++ni)
#pragma unroll
      for (int ks = 0; ks < 2; ++ks)
        bfr[ni][ks] = *(const short8*)(W + (ni * 16 + l15) * 64 + ks * 32 + quad * 8);
    f32x4 acc[2][4] = {};
#pragma unroll
    for (int mi = 0; mi < 2; ++mi)
#pragma unroll
      for (int ni = 0; ni < 4; ++ni)
#pragma unroll
        for (int ks = 0; ks < 2; ++ks)
          acc[mi][ni] = __builtin_amdgcn_mfma_f32_16x16x32_bf16(af[mi][ks], bfr[ni][ks],
                                                                acc[mi][ni], 0, 0, 0);
    ushort_t* O = Os[wsel];
#pragma unroll
    for (int mi = 0; mi < 2; ++mi)
#pragma unroll
      for (int ni = 0; ni < 4; ++ni)
#pragma unroll
        for (int r = 0; r < 4; ++r) {
          long rg = rowbase + w * 32 + mi * 16 + quad * 4 + r;
          O[rg * 64 + ni * 16 + l15] = f2bf(acc[mi][ni][r]);
        }
  }
}

// ---------------- flash attention: grid (32 qtiles, 64 batch-heads) ---------
// LDS strides padded to 72 elems (144B rows) -> bank-spread b128 access.
#define KSTR 72
__global__ __launch_bounds__(256) void attn_k(const ushort_t* __restrict__ q,
                                              const ushort_t* __restrict__ kk,
                                              const ushort_t* __restrict__ vv,
                                              ushort_t* __restrict__ ctx) {
  __shared__ __align__(16) ushort_t sm[64 * KSTR * 2 + 4 * 16 * KSTR];
  ushort_t* Ks = sm;                    // [key][KSTR]
  ushort_t* Vt = sm + 64 * KSTR;        // [d][KSTR]  (V^T tile)
  ushort_t* Ps = sm + 128 * KSTR;       // 4 waves x [16 q][KSTR]
  int t = threadIdx.x;
  int qt = blockIdx.x, bh = blockIdx.y;
  int n = bh >> 4, h = bh & 15;
  long qtok0 = (long)n * SEQ + qt * 64;
  int w = t >> 6, lane = t & 63, l15 = lane & 15, quad = lane >> 4;
  // Q fragments once, straight from global (row = w*16+l15, k-chunks quad*8)
  short8 qf[2];
#pragma unroll
  for (int ks = 0; ks < 2; ++ks)
    qf[ks] = *(const short8*)(q + (qtok0 + w * 16 + l15) * EMBED + h * HDIM + ks * 32 + quad * 8);
  float m_run[4] = {-1e30f, -1e30f, -1e30f, -1e30f};
  float l_run[4] = {0.f, 0.f, 0.f, 0.f};
  f32x4 acc_o[4] = {};
  const float sc = 1.0f / 32.0f;  // 1/sqrt(EMBED)
  for (int kt = 0; kt < SEQ / 64; ++kt) {
    long ktok0 = (long)n * SEQ + kt * 64;
    // K: coalesced global -> regs -> b128 LDS (bank-spread via stride 72)
    short8 kreg[2];
#pragma unroll
    for (int p = 0; p < 2; ++p) {
      int idx = p * 256 + t;
      int key = idx >> 3, chunk = idx & 7;
      kreg[p] = *(const short8*)(kk + (ktok0 + key) * EMBED + h * HDIM + chunk * 8);
    }
    // V: lane = key (consecutive keys in consecutive lanes) -> transpose
    // writes hit consecutive LDS elements (conflict-free).
    short8 vreg[2];
#pragma unroll
    for (int p = 0; p < 2; ++p) {
      int idx = p * 256 + t;
      int key = idx & 63, c = idx >> 6;
      vreg[p] = *(const short8*)(vv + (ktok0 + key) * EMBED + h * HDIM + c * 8);
    }
    __syncthreads();  // previous tile's readers done
#pragma unroll
    for (int p = 0; p < 2; ++p) {
      int idx = p * 256 + t;
      int key = idx >> 3, chunk = idx & 7;
      *(short8*)(Ks + key * KSTR + chunk * 8) = kreg[p];
    }
#pragma unroll
    for (int p = 0; p < 2; ++p) {
      int idx = p * 256 + t;
      int key = idx & 63, c = idx >> 6;
#pragma unroll
      for (int j = 0; j < 8; ++j) Vt[(c * 8 + j) * KSTR + key] = (ushort_t)vreg[p][j];
    }
    __syncthreads();
    // S = Q K^T  (16 q-rows per wave x 64 keys)
    f32x4 s[4] = {};
#pragma unroll
    for (int ks = 0; ks < 2; ++ks) {
#pragma unroll
      for (int nf = 0; nf < 4; ++nf) {
        short8 bb = *(const short8*)(Ks + (nf * 16 + l15) * KSTR + ks * 32 + quad * 8);
        s[nf] = __builtin_amdgcn_mfma_f32_16x16x32_bf16(qf[ks], bb, s[nf], 0, 0, 0);
      }
    }
#pragma unroll
    for (int nf = 0; nf < 4; ++nf)
#pragma unroll
      for (int j = 0; j < 4; ++j) s[nf][j] *= sc;
    // online softmax; lane holds rows quad*4+j, cols nf*16+l15
    float mnew[4], alpha[4];
#pragma unroll
    for (int j = 0; j < 4; ++j) {
      float m = fmaxf(fmaxf(s[0][j], s[1][j]), fmaxf(s[2][j], s[3][j]));
#pragma unroll
      for (int d = 1; d < 16; d <<= 1) m = fmaxf(m, __shfl_xor(m, d, 64));
      mnew[j] = fmaxf(m_run[j], m);
      alpha[j] = __expf(m_run[j] - mnew[j]);
      m_run[j] = mnew[j];
    }
    float rsum[4] = {0.f, 0.f, 0.f, 0.f};
#pragma unroll
    for (int nf = 0; nf < 4; ++nf)
#pragma unroll
      for (int j = 0; j < 4; ++j) {
        float p = __expf(s[nf][j] - mnew[j]);
        s[nf][j] = p;
        rsum[j] += p;
      }
#pragma unroll
    for (int j = 0; j < 4; ++j) {
      float r = rsum[j];
#pragma unroll
      for (int d = 1; d < 16; d <<= 1) r += __shfl_xor(r, d, 64);
      l_run[j] = l_run[j] * alpha[j] + r;
    }
#pragma unroll
    for (int nf = 0; nf < 4; ++nf)
#pragma unroll
      for (int j = 0; j < 4; ++j) acc_o[nf][j] *= alpha[j];
    // P -> LDS (C-layout -> A-layout round trip), wave-private, stride 72
    ushort_t* Pw = Ps + w * 16 * KSTR;
#pragma unroll
    for (int nf = 0; nf < 4; ++nf)
#pragma unroll
      for (int j = 0; j < 4; ++j)
        Pw[(quad * 4 + j) * KSTR + nf * 16 + l15] = f2bf(s[nf][j]);
    // O += P V
#pragma unroll
    for (int ks = 0; ks < 2; ++ks) {
      short8 a = *(const short8*)(Pw + l15 * KSTR + ks * 32 + quad * 8);
#pragma unroll
      for (int nf = 0; nf < 4; ++nf) {
        short8 bb = *(const short8*)(Vt + (nf * 16 + l15) * KSTR + ks * 32 + quad * 8);
        acc_o[nf] = __builtin_amdgcn_mfma_f32_16x16x32_bf16(a, bb, acc_o[nf], 0, 0, 0);
      }
    }
  }
#pragma unroll
  for (int nf = 0; nf < 4; ++nf)
#pragma unroll
    for (int j = 0; j < 4; ++j) {
      long tok = qtok0 + w * 16 + quad * 4 + j;
      float inv_l = 1.0f / fmaxf(l_run[j], 1e-30f);
      ctx[(tok * HEADS + h) * HDIM + nf * 16 + l15] = f2bf(acc_o[nf][j] * inv_l);
    }
}

// ---------------- gemm_bt 128x128, BK=32, fused epilogues -------------------
// mode 0: out_f  = acc + bias + res        (f32 out; res = x, f32)
// mode 1: out_bf = gelu_exact(acc + bias)
// mode 2: out_f  = acc + bias + res        (f32 OUT -> d_out; res = attn_out)
__global__ __launch_bounds__(256) void gemm_bt(const ushort_t* __restrict__ A,
                                               const ushort_t* __restrict__ BT,
                                               const float* __restrict__ bias,
                                               const float* __restrict__ res,
                                               ushort_t* __restrict__ out_bf,
                                               float* __restrict__ out_f,
                                               int M, int N, int K, int mode) {
  __shared__ __align__(16) ushort_t As[128 * 32];
  __shared__ __align__(16) ushort_t Bs[128 * 32];
  int t = threadIdx.x;
  long m0 = (long)blockIdx.y * 128;
  long n0 = (long)blockIdx.x * 128;
  int w = t >> 6, lane = t & 63, l15 = lane & 15, quad = lane >> 4;
  int wm = w >> 1, wn = w & 1;
  f32x4 acc[4][4] = {};
  for (int kt = 0; kt < K; kt += 32) {
    __syncthreads();
#pragma unroll
    for (int p = 0; p < 2; ++p) {
      int idx = p * 256 + t;         // 512 chunks of 16B per tile
      int row = idx >> 2, chunk = idx & 3;
      g2lds16(A + (m0 + row) * K + kt + chunk * 8, As + idx * 8);
      g2lds16(BT + (n0 + row) * K + kt + chunk * 8, Bs + idx * 8);
    }
    __syncthreads();
    short8 af[4], bfr[4];
#pragma unroll
    for (int mi = 0; mi < 4; ++mi)
      af[mi] = *(const short8*)(As + (wm * 64 + mi * 16 + l15) * 32 + quad * 8);
#pragma unroll
    for (int ni = 0; ni < 4; ++ni)
      bfr[ni] = *(const short8*)(Bs + (wn * 64 + ni * 16 + l15) * 32 + quad * 8);
#pragma unroll
    for (int mi = 0; mi < 4; ++mi)
#pragma unroll
      for (int ni = 0; ni < 4; ++ni)
        acc[mi][ni] = __builtin_amdgcn_mfma_f32_16x16x32_bf16(af[mi], bfr[ni], acc[mi][ni], 0, 0, 0);
  }
#pragma unroll
  for (int mi = 0; mi < 4; ++mi)
#pragma unroll
    for (int ni = 0; ni < 4; ++ni) {
      long col = n0 + wn * 64 + ni * 16 + l15;
      float bv = bias[col];
#pragma unroll
      for (int r = 0; r < 4; ++r) {
        long row = m0 + wm * 64 + mi * 16 + quad * 4 + r;
        long off = row * N + col;
        float val = acc[mi][ni][r] + bv;
        if (mode == 0) {
          out_f[off] = val + res[off];
        } else if (mode == 1) {
          val = 0.5f * val * (1.0f + erff(val * 0.70710678118654752f));
          out_bf[off] = f2bf(val);
        } else {
          out_f[off] = val + res[off];   // f32 final output
        }
      }
    }
}

extern "C" void kernel_launch(void* const* d_in, const int* in_sizes, int n_in,
                              void* d_out, int out_size, void* d_ws, size_t ws_size,
                              hipStream_t stream) {
  (void)in_sizes; (void)n_in; (void)out_size; (void)ws_size;
  const float* x   = (const float*)d_in[0];
  const float* Wq  = (const float*)d_in[1];
  const float* Wk  = (const float*)d_in[2];
  const float* Wv  = (const float*)d_in[3];
  const float* Wo  = (const float*)d_in[4];
  const float* bo  = (const float*)d_in[5];
  const float* l1g = (const float*)d_in[6];
  const float* l1b = (const float*)d_in[7];
  const float* l2g = (const float*)d_in[8];
  const float* l2b = (const float*)d_in[9];
  const float* W1  = (const float*)d_in[10];
  const float* b1  = (const float*)d_in[11];
  const float* W2  = (const float*)d_in[12];
  const float* b2  = (const float*)d_in[13];
  float* out = (float*)d_out;

  char* ws = (char*)d_ws;
  const size_t MB = 1ull << 20;
  ushort_t* XN  = (ushort_t*)(ws);            // 16MB [0,16)  ; reused as CTX
  ushort_t* Q   = (ushort_t*)(ws + 16 * MB);  // 16MB [16,32)
  ushort_t* Kb  = (ushort_t*)(ws + 32 * MB);  // 16MB [32,48)
  ushort_t* Vb  = (ushort_t*)(ws + 48 * MB);  // 16MB [48,64)
  float*    AO  = (float*)(ws + 64 * MB);     // 32MB [64,96)
  ushort_t* CTX = XN;
  ushort_t* AN  = (ushort_t*)(ws + 96 * MB);  // 16MB [96,112)
  ushort_t* FF1 = (ushort_t*)(ws);            // 64MB [0,64) over XN/Q/K/V (dead)
  ushort_t* WoT = (ushort_t*)(ws + 112 * MB); // 2MB
  ushort_t* W1T = (ushort_t*)(ws + 114 * MB); // 8MB
  ushort_t* W2T = (ushort_t*)(ws + 122 * MB); // 8MB
  ushort_t* WqT = (ushort_t*)(ws + 130 * MB);
  ushort_t* WkT = WqT + 4096;
  ushort_t* WvT = WkT + 4096;                 // total < 131MB

  dim3 b256(256);
  transpose_cast_k<<<dim3(2, 2), b256, 0, stream>>>(Wq, WqT, 64, 64);
  transpose_cast_k<<<dim3(2, 2), b256, 0, stream>>>(Wk, WkT, 64, 64);
  transpose_cast_k<<<dim3(2, 2), b256, 0, stream>>>(Wv, WvT, 64, 64);
  transpose_cast_k<<<dim3(32, 32), b256, 0, stream>>>(Wo, WoT, 1024, 1024);
  transpose_cast_k<<<dim3(128, 32), b256, 0, stream>>>(W1, W1T, 1024, 4096);
  transpose_cast_k<<<dim3(32, 128), b256, 0, stream>>>(W2, W2T, 4096, 1024);

  ln_k<<<dim3(TOKENS), b256, 0, stream>>>(x, l1g, l1b, XN);
  qkv_k<<<dim3(1024), b256, 0, stream>>>(XN, WqT, WkT, WvT, Q, Kb, Vb);
  attn_k<<<dim3(32, 64), b256, 0, stream>>>(Q, Kb, Vb, CTX);
  gemm_bt<<<dim3(8, 64), b256, 0, stream>>>(CTX, WoT, bo, x, nullptr, AO,
                                            TOKENS, EMBED, EMBED, 0);
  ln_k<<<dim3(TOKENS), b256, 0, stream>>>(AO, l2g, l2b, AN);
  gemm_bt<<<dim3(32, 64), b256, 0, stream>>>(AN, W1T, b1, nullptr, FF1, nullptr,
                                             TOKENS, 4096, EMBED, 1);
  gemm_bt<<<dim3(8, 64), b256, 0, stream>>>(FF1, W2T, b2, AO, nullptr, out,
                                            TOKENS, EMBED, 4096, 2);
}

// Round 6
// 622.097 us; speedup vs baseline: 1.4447x; 1.1640x over previous
//
#include <hip/hip_runtime.h>
#include <hip/hip_bf16.h>
#include <cstdint>
#include <math.h>

#define EMBED 1024
#define HEADS 16
#define HDIM 64
#define SEQ 2048
#define TOKENS 8192   // 4*2048

typedef __attribute__((ext_vector_type(8))) short short8;
typedef __attribute__((ext_vector_type(4))) float f32x4;
typedef unsigned short ushort_t;

__device__ __forceinline__ float bf2f(ushort_t u) {
  union { unsigned int i; float f; } c; c.i = ((unsigned int)u) << 16; return c.f;
}
__device__ __forceinline__ ushort_t f2bf(float f) {
  union { float f; unsigned int i; } c; c.f = f;
  unsigned int x = c.i;
  unsigned int r = x + 0x7fffu + ((x >> 16) & 1u);  // RNE
  return (ushort_t)(r >> 16);
}
// pack two f32 -> two bf16 (round-half-up) in one dword: {hi=b, lo=a}
__device__ __forceinline__ unsigned int pack_bf16_rhu(float a, float b) {
  unsigned int ua = __float_as_uint(a) + 0x8000u;
  unsigned int ub = __float_as_uint(b) + 0x8000u;
  return __builtin_amdgcn_perm(ub, ua, 0x07060302u);
}
__device__ __forceinline__ void g2lds16(const void* g, void* l) {
  __builtin_amdgcn_global_load_lds(
      (const __attribute__((address_space(1))) unsigned int*)g,
      (__attribute__((address_space(3))) unsigned int*)l, 16, 0, 0);
}

// ---------- prep: transpose + cast f32 -> bf16: out[c][r] = bf16(in[r][c]) --
__global__ __launch_bounds__(256) void transpose_cast_k(const float* __restrict__ in,
                                                        ushort_t* __restrict__ out,
                                                        int R, int C) {
  __shared__ ushort_t tile[32][33];
  int tx = threadIdx.x & 31, ty = threadIdx.x >> 5;
  int c0 = blockIdx.x * 32, r0 = blockIdx.y * 32;
#pragma unroll
  for (int i = ty; i < 32; i += 8)
    tile[i][tx] = f2bf(in[(long)(r0 + i) * C + (c0 + tx)]);
  __syncthreads();
#pragma unroll
  for (int i = ty; i < 32; i += 8) out[(long)(c0 + i) * R + (r0 + tx)] = tile[tx][i];
}

// ---------- layernorm rows of 1024, f32 in -> bf16 out ----------
__global__ __launch_bounds__(256) void ln_k(const float* __restrict__ xin,
                                            const float* __restrict__ g,
                                            const float* __restrict__ b,
                                            ushort_t* __restrict__ out) {
  int row = blockIdx.x, t = threadIdx.x;
  long base = (long)row * EMBED + t * 4;
  f32x4 xv = *(const f32x4*)(xin + base);
  float v[4] = {xv[0], xv[1], xv[2], xv[3]};
  float s1 = v[0] + v[1] + v[2] + v[3];
  float s2 = v[0]*v[0] + v[1]*v[1] + v[2]*v[2] + v[3]*v[3];
#pragma unroll
  for (int m = 1; m < 64; m <<= 1) { s1 += __shfl_xor(s1, m, 64); s2 += __shfl_xor(s2, m, 64); }
  __shared__ float ws1[4], ws2[4];
  int w = t >> 6, lane = t & 63;
  if (lane == 0) { ws1[w] = s1; ws2[w] = s2; }
  __syncthreads();
  float S1 = ws1[0] + ws1[1] + ws1[2] + ws1[3];
  float S2 = ws2[0] + ws2[1] + ws2[2] + ws2[3];
  float mean = S1 * (1.0f / EMBED);
  float var = S2 * (1.0f / EMBED) - mean * mean;
  float rstd = rsqrtf(var + 1e-5f);
#pragma unroll
  for (int j = 0; j < 4; ++j) {
    int c = t * 4 + j;
    out[(long)row * EMBED + c] = f2bf((v[j] - mean) * rstd * g[c] + b[c]);
  }
}

// ---------------- fused QKV: [131072,64] x (64x64)^T x3 ----------------
// Q output is pre-scaled by 1/sqrt(EMBED) = 1/32 (folded out of attention).
__global__ __launch_bounds__(256) void qkv_k(const ushort_t* __restrict__ xn,
                                             const ushort_t* __restrict__ WqT,
                                             const ushort_t* __restrict__ WkT,
                                             const ushort_t* __restrict__ WvT,
                                             ushort_t* __restrict__ q, ushort_t* __restrict__ k,
                                             ushort_t* __restrict__ v) {
  __shared__ __align__(16) ushort_t As[128 * 64];  // 16KB
  int t = threadIdx.x;
  long rowbase = (long)blockIdx.x * 128;
#pragma unroll
  for (int p = 0; p < 4; ++p) {
    int idx = p * 256 + t;             // 1024 chunks of 16B
    int row = idx >> 3, chunk = idx & 7;
    g2lds16(xn + (rowbase + row) * 64 + chunk * 8, As + idx * 8);
  }
  __syncthreads();
  int w = t >> 6, lane = t & 63, l15 = lane & 15, quad = lane >> 4;
  short8 af[2][2];
#pragma unroll
  for (int mi = 0; mi < 2; ++mi)
#pragma unroll
    for (int ks = 0; ks < 2; ++ks)
      af[mi][ks] = *(const short8*)(As + (w * 32 + mi * 16 + l15) * 64 + ks * 32 + quad * 8);
  const ushort_t* Ws[3] = {WqT, WkT, WvT};
  ushort_t* Os[3] = {q, k, v};
#pragma unroll
  for (int wsel = 0; wsel < 3; ++wsel) {
    const ushort_t* W = Ws[wsel];
    float oscale = (wsel == 0) ? 0.03125f : 1.0f;
    short8 bfr[4][2];
#pragma unroll
    for (int ni = 0; ni < 4; ++ni)
#pragma unroll
      for (int ks = 0; ks < 2; ++ks)
        bfr[ni][ks] = *(const short8*)(W + (ni * 16 + l15) * 64 + ks * 32 + quad * 8);
    f32x4 acc[2][4] = {};
#pragma unroll
    for (int mi = 0; mi < 2; ++mi)
#pragma unroll
      for (int ni = 0; ni < 4; ++ni)
#pragma unroll
        for (int ks = 0; ks < 2; ++ks)
          acc[mi][ni] = __builtin_amdgcn_mfma_f32_16x16x32_bf16(af[mi][ks], bfr[ni][ks],
                                                                acc[mi][ni], 0, 0, 0);
    ushort_t* O = Os[wsel];
#pragma unroll
    for (int mi = 0; mi < 2; ++mi)
#pragma unroll
      for (int ni = 0; ni < 4; ++ni)
#pragma unroll
        for (int r = 0; r < 4; ++r) {
          long rg = rowbase + w * 32 + mi * 16 + quad * 4 + r;
          O[rg * 64 + ni * 16 + l15] = f2bf(acc[mi][ni][r] * oscale);
        }
  }
}

// ---------------- flash attention: grid (32 qtiles, 64 batch-heads) ---------
// S^T formulation: S^T = mfma(K,Q) puts each lane's own q-column in-lane, so
// softmax is in-lane + 2 shfl and P feeds PV's B operand STRAIGHT FROM
// REGISTERS. The arbitrary MFMA contraction ordering is matched by storing
// V^T's key columns permuted: rho = (k&32)|((k&12)<<1)|((k&16)>>2)|(k&3).
#define KSTR 72
__global__ __launch_bounds__(256) void attn_k(const ushort_t* __restrict__ q,
                                              const ushort_t* __restrict__ kk,
                                              const ushort_t* __restrict__ vv,
                                              ushort_t* __restrict__ ctx) {
  __shared__ __align__(16) ushort_t sm[64 * KSTR * 2];
  ushort_t* Ks = sm;                    // [key][KSTR]
  ushort_t* Vt = sm + 64 * KSTR;        // [d][KSTR], key-permuted columns
  int t = threadIdx.x;
  int qt = blockIdx.x, bh = blockIdx.y;
  int n = bh >> 4, h = bh & 15;
  long qtok0 = (long)n * SEQ + qt * 64;
  int w = t >> 6, lane = t & 63, l15 = lane & 15, quad = lane >> 4;
  // Q fragments once from global (pre-scaled by 1/32 in qkv_k)
  short8 qf[2];
#pragma unroll
  for (int ks = 0; ks < 2; ++ks)
    qf[ks] = *(const short8*)(q + (qtok0 + w * 16 + l15) * EMBED + h * HDIM + ks * 32 + quad * 8);
  // V staging: this lane stages actual key vkey into permuted column vcol
  int vkey = t & 63;
  int vcol = (vkey & 32) | ((vkey & 12) << 1) | ((vkey & 16) >> 2) | (vkey & 3);
  float m_run = -1e30f, l_run = 0.f;
  f32x4 acc_o[4] = {};   // O^T: [d-block nf][r], d = nf*16+quad*4+r, q = l15
  for (int kt = 0; kt < SEQ / 64; ++kt) {
    long ktok0 = (long)n * SEQ + kt * 64;
    short8 kreg[2];
#pragma unroll
    for (int p = 0; p < 2; ++p) {
      int idx = p * 256 + t;
      int key = idx >> 3, chunk = idx & 7;
      kreg[p] = *(const short8*)(kk + (ktok0 + key) * EMBED + h * HDIM + chunk * 8);
    }
    short8 vreg[2];
#pragma unroll
    for (int p = 0; p < 2; ++p) {
      int c = p * 4 + (t >> 6);
      vreg[p] = *(const short8*)(vv + (ktok0 + vkey) * EMBED + h * HDIM + c * 8);
    }
    __syncthreads();  // previous tile's readers done
#pragma unroll
    for (int p = 0; p < 2; ++p) {
      int idx = p * 256 + t;
      int key = idx >> 3, chunk = idx & 7;
      *(short8*)(Ks + key * KSTR + chunk * 8) = kreg[p];
    }
#pragma unroll
    for (int p = 0; p < 2; ++p) {
      int c = p * 4 + (t >> 6);
#pragma unroll
      for (int j = 0; j < 8; ++j) Vt[(c * 8 + j) * KSTR + vcol] = (ushort_t)vreg[p][j];
    }
    __syncthreads();
    // S^T[key][q] = mfma(A=K, B=Q): lane holds q=l15, keys nf*16+quad*4+r
    f32x4 st[4] = {};
#pragma unroll
    for (int ks = 0; ks < 2; ++ks) {
#pragma unroll
      for (int nf = 0; nf < 4; ++nf) {
        short8 kf = *(const short8*)(Ks + (nf * 16 + l15) * KSTR + ks * 32 + quad * 8);
        st[nf] = __builtin_amdgcn_mfma_f32_16x16x32_bf16(kf, qf[ks], st[nf], 0, 0, 0);
      }
    }
    // online softmax over keys: in-lane 16 values + cross-quad xor(16,32)
    float mx = st[0][0];
#pragma unroll
    for (int nf = 0; nf < 4; ++nf)
#pragma unroll
      for (int r = 0; r < 4; ++r) mx = fmaxf(mx, st[nf][r]);
    mx = fmaxf(mx, __shfl_xor(mx, 16, 64));
    mx = fmaxf(mx, __shfl_xor(mx, 32, 64));
    float mnew = fmaxf(m_run, mx);
    float alpha = __expf(m_run - mnew);
    m_run = mnew;
    float rsum = 0.f;
#pragma unroll
    for (int nf = 0; nf < 4; ++nf)
#pragma unroll
      for (int r = 0; r < 4; ++r) {
        float pv = __expf(st[nf][r] - mnew);
        st[nf][r] = pv;
        rsum += pv;
      }
    rsum += __shfl_xor(rsum, 16, 64);
    rsum += __shfl_xor(rsum, 32, 64);
    l_run = l_run * alpha + rsum;
#pragma unroll
    for (int nf = 0; nf < 4; ++nf)
#pragma unroll
      for (int r = 0; r < 4; ++r) acc_o[nf][r] *= alpha;
    // pack P (in-register) -> B-operand fragments; key order matches Vt perm
    unsigned int Dk[4][2];
#pragma unroll
    for (int nf = 0; nf < 4; ++nf)
#pragma unroll
      for (int hh = 0; hh < 2; ++hh)
        Dk[nf][hh] = pack_bf16_rhu(st[nf][2 * hh], st[nf][2 * hh + 1]);
    // O^T += mfma(A=V^T, B=P)
#pragma unroll
    for (int ks = 0; ks < 2; ++ks) {
      union { unsigned int u[4]; short8 s8; } pf;
      pf.u[0] = Dk[2 * ks][0];
      pf.u[1] = Dk[2 * ks][1];
      pf.u[2] = Dk[2 * ks + 1][0];
      pf.u[3] = Dk[2 * ks + 1][1];
#pragma unroll
      for (int nf = 0; nf < 4; ++nf) {
        short8 vf = *(const short8*)(Vt + (nf * 16 + l15) * KSTR + ks * 32 + quad * 8);
        acc_o[nf] = __builtin_amdgcn_mfma_f32_16x16x32_bf16(vf, pf.s8, acc_o[nf], 0, 0, 0);
      }
    }
  }
  // epilogue: O^T lane holds d = nf*16+quad*4+r for its q = w*16+l15
  float inv_l = 1.0f / fmaxf(l_run, 1e-30f);
  long tok = qtok0 + w * 16 + l15;
#pragma unroll
  for (int nf = 0; nf < 4; ++nf) {
    unsigned int d0 = pack_bf16_rhu(acc_o[nf][0] * inv_l, acc_o[nf][1] * inv_l);
    unsigned int d1 = pack_bf16_rhu(acc_o[nf][2] * inv_l, acc_o[nf][3] * inv_l);
    unsigned int* dst = (unsigned int*)(ctx + tok * EMBED + h * HDIM + nf * 16 + quad * 4);
    dst[0] = d0;
    dst[1] = d1;
  }
}

// ---------------- gemm_bt 128x128, BK=32, fused epilogues -------------------
// mode 0: out_f  = acc + bias + res        (f32 out; res = x, f32)
// mode 1: out_bf = gelu_exact(acc + bias)
// mode 2: out_f  = acc + bias + res        (f32 OUT -> d_out; res = attn_out)
__global__ __launch_bounds__(256) void gemm_bt(const ushort_t* __restrict__ A,
                                               const ushort_t* __restrict__ BT,
                                               const float* __restrict__ bias,
                                               const float* __restrict__ res,
                                               ushort_t* __restrict__ out_bf,
                                               float* __restrict__ out_f,
                                               int M, int N, int K, int mode) {
  __shared__ __align__(16) ushort_t As[128 * 32];
  __shared__ __align__(16) ushort_t Bs[128 * 32];
  int t = threadIdx.x;
  long m0 = (long)blockIdx.y * 128;
  long n0 = (long)blockIdx.x * 128;
  int w = t >> 6, lane = t & 63, l15 = lane & 15, quad = lane >> 4;
  int wm = w >> 1, wn = w & 1;
  f32x4 acc[4][4] = {};
  for (int kt = 0; kt < K; kt += 32) {
    __syncthreads();
#pragma unroll
    for (int p = 0; p < 2; ++p) {
      int idx = p * 256 + t;         // 512 chunks of 16B per tile
      int row = idx >> 2, chunk = idx & 3;
      g2lds16(A + (m0 + row) * K + kt + chunk * 8, As + idx * 8);
      g2lds16(BT + (n0 + row) * K + kt + chunk * 8, Bs + idx * 8);
    }
    __syncthreads();
    short8 af[4], bfr[4];
#pragma unroll
    for (int mi = 0; mi < 4; ++mi)
      af[mi] = *(const short8*)(As + (wm * 64 + mi * 16 + l15) * 32 + quad * 8);
#pragma unroll
    for (int ni = 0; ni < 4; ++ni)
      bfr[ni] = *(const short8*)(Bs + (wn * 64 + ni * 16 + l15) * 32 + quad * 8);
#pragma unroll
    for (int mi = 0; mi < 4; ++mi)
#pragma unroll
      for (int ni = 0; ni < 4; ++ni)
        acc[mi][ni] = __builtin_amdgcn_mfma_f32_16x16x32_bf16(af[mi], bfr[ni], acc[mi][ni], 0, 0, 0);
  }
#pragma unroll
  for (int mi = 0; mi < 4; ++mi)
#pragma unroll
    for (int ni = 0; ni < 4; ++ni) {
      long col = n0 + wn * 64 + ni * 16 + l15;
      float bv = bias[col];
#pragma unroll
      for (int r = 0; r < 4; ++r) {
        long row = m0 + wm * 64 + mi * 16 + quad * 4 + r;
        long off = row * N + col;
        float val = acc[mi][ni][r] + bv;
        if (mode == 0) {
          out_f[off] = val + res[off];
        } else if (mode == 1) {
          val = 0.5f * val * (1.0f + erff(val * 0.70710678118654752f));
          out_bf[off] = f2bf(val);
        } else {
          out_f[off] = val + res[off];   // f32 final output
        }
      }
    }
}

extern "C" void kernel_launch(void* const* d_in, const int* in_sizes, int n_in,
                              void* d_out, int out_size, void* d_ws, size_t ws_size,
                              hipStream_t stream) {
  (void)in_sizes; (void)n_in; (void)out_size; (void)ws_size;
  const float* x   = (const float*)d_in[0];
  const float* Wq  = (const float*)d_in[1];
  const float* Wk  = (const float*)d_in[2];
  const float* Wv  = (const float*)d_in[3];
  const float* Wo  = (const float*)d_in[4];
  const float* bo  = (const float*)d_in[5];
  const float* l1g = (const float*)d_in[6];
  const float* l1b = (const float*)d_in[7];
  const float* l2g = (const float*)d_in[8];
  const float* l2b = (const float*)d_in[9];
  const float* W1  = (const float*)d_in[10];
  const float* b1  = (const float*)d_in[11];
  const float* W2  = (const float*)d_in[12];
  const float* b2  = (const float*)d_in[13];
  float* out = (float*)d_out;

  char* ws = (char*)d_ws;
  const size_t MB = 1ull << 20;
  ushort_t* XN  = (ushort_t*)(ws);            // 16MB [0,16)  ; reused as CTX
  ushort_t* Q   = (ushort_t*)(ws + 16 * MB);  // 16MB [16,32)
  ushort_t* Kb  = (ushort_t*)(ws + 32 * MB);  // 16MB [32,48)
  ushort_t* Vb  = (ushort_t*)(ws + 48 * MB);  // 16MB [48,64)
  float*    AO  = (float*)(ws + 64 * MB);     // 32MB [64,96)
  ushort_t* CTX = XN;
  ushort_t* AN  = (ushort_t*)(ws + 96 * MB);  // 16MB [96,112)
  ushort_t* FF1 = (ushort_t*)(ws);            // 64MB [0,64) over XN/Q/K/V (dead)
  ushort_t* WoT = (ushort_t*)(ws + 112 * MB); // 2MB
  ushort_t* W1T = (ushort_t*)(ws + 114 * MB); // 8MB
  ushort_t* W2T = (ushort_t*)(ws + 122 * MB); // 8MB
  ushort_t* WqT = (ushort_t*)(ws + 130 * MB);
  ushort_t* WkT = WqT + 4096;
  ushort_t* WvT = WkT + 4096;                 // total < 131MB

  dim3 b256(256);
  transpose_cast_k<<<dim3(2, 2), b256, 0, stream>>>(Wq, WqT, 64, 64);
  transpose_cast_k<<<dim3(2, 2), b256, 0, stream>>>(Wk, WkT, 64, 64);
  transpose_cast_k<<<dim3(2, 2), b256, 0, stream>>>(Wv, WvT, 64, 64);
  transpose_cast_k<<<dim3(32, 32), b256, 0, stream>>>(Wo, WoT, 1024, 1024);
  transpose_cast_k<<<dim3(128, 32), b256, 0, stream>>>(W1, W1T, 1024, 4096);
  transpose_cast_k<<<dim3(32, 128), b256, 0, stream>>>(W2, W2T, 4096, 1024);

  ln_k<<<dim3(TOKENS), b256, 0, stream>>>(x, l1g, l1b, XN);
  qkv_k<<<dim3(1024), b256, 0, stream>>>(XN, WqT, WkT, WvT, Q, Kb, Vb);
  attn_k<<<dim3(32, 64), b256, 0, stream>>>(Q, Kb, Vb, CTX);
  gemm_bt<<<dim3(8, 64), b256, 0, stream>>>(CTX, WoT, bo, x, nullptr, AO,
                                            TOKENS, EMBED, EMBED, 0);
  ln_k<<<dim3(TOKENS), b256, 0, stream>>>(AO, l2g, l2b, AN);
  gemm_bt<<<dim3(32, 64), b256, 0, stream>>>(AN, W1T, b1, nullptr, FF1, nullptr,
                                             TOKENS, 4096, EMBED, 1);
  gemm_bt<<<dim3(8, 64), b256, 0, stream>>>(FF1, W2T, b2, AO, nullptr, out,
                                            TOKENS, EMBED, 4096, 2);
}